// Round 8
// baseline (589.214 us; speedup 1.0000x reference)
//
#include <hip/hip_runtime.h>
#include <stdint.h>

#define DHID 64       // hidden dim, fixed by problem
#define G_BLOCKS 1024 // blocks in phase-A partition kernels
#define BMAX 1024     // max buckets (bucket = 128 rows; n <= 131072)
#define RPB 128       // rows per bucket
#define CAP 4608      // LDS edge buffer per bucket (mean 4093 + ~8 sigma)
#define PH_SHIFT 14   // column-phase width = 16384 rows of x (4.2 MB slice)
#define NPHMAX 8      // covers n < 131072
#define NKEY (NPHMAX * RPB)

static inline size_t align256(size_t x) { return (x + 255) & ~(size_t)255; }

// ---------------- generic helpers ----------------

__global__ void zero_f32(float* __restrict__ p, size_t n) {
  size_t i = (size_t)blockIdx.x * blockDim.x + threadIdx.x;
  if (i < n) p[i] = 0.f;
}

// ---------------- phase A: bucket partition (bucket = row >> 7) ----------------
// (frozen from round 6 — verified)

__global__ __launch_bounds__(256) void
a1_hist_k(const int* __restrict__ row, int* __restrict__ histGB,
          int nnz, int B, int chunk) {
  __shared__ int h[BMAX];
  for (int i = threadIdx.x; i < B; i += 256) h[i] = 0;
  __syncthreads();
  int g = blockIdx.x;
  int s = g * chunk, e = min(nnz, s + chunk);
  int j = s + threadIdx.x;
  for (; j + 768 < e; j += 1024) {
    int r0 = row[j], r1 = row[j + 256], r2 = row[j + 512], r3 = row[j + 768];
    atomicAdd(&h[r0 >> 7], 1);
    atomicAdd(&h[r1 >> 7], 1);
    atomicAdd(&h[r2 >> 7], 1);
    atomicAdd(&h[r3 >> 7], 1);
  }
  for (; j < e; j += 256)
    atomicAdd(&h[row[j] >> 7], 1);
  __syncthreads();
  for (int i = threadIdx.x; i < B; i += 256)
    histGB[i * G_BLOCKS + g] = h[i];
}

__global__ __launch_bounds__(256) void
scan_gb_k(const int* __restrict__ histGB, int* __restrict__ offGB,
          int* __restrict__ btot, int B) {
  __shared__ int wsum[4];
  int b = blockIdx.x, t = threadIdx.x, lane = t & 63, w = t >> 6;
  int v[4];
  int s4 = 0;
#pragma unroll
  for (int i = 0; i < 4; ++i) {
    v[i] = histGB[b * G_BLOCKS + t * 4 + i];
    s4 += v[i];
  }
  int incl = s4;
#pragma unroll
  for (int off = 1; off < 64; off <<= 1) {
    int u = __shfl_up(incl, off);
    if (lane >= off) incl += u;
  }
  if (lane == 63) wsum[w] = incl;
  __syncthreads();
  int run = incl - s4;
  for (int w2 = 0; w2 < w; ++w2) run += wsum[w2];
#pragma unroll
  for (int i = 0; i < 4; ++i) {
    offGB[b * G_BLOCKS + t * 4 + i] = run;
    run += v[i];
  }
  if (t == 0) btot[b] = wsum[0] + wsum[1] + wsum[2] + wsum[3];
}

__global__ void scan_b_k(const int* __restrict__ btot, int* __restrict__ base, int B) {
  __shared__ int wsum[4];
  int t = threadIdx.x, lane = t & 63, w = t >> 6;
  int v[8];
  int s = 0;
#pragma unroll
  for (int i = 0; i < 8; ++i) {
    int idx = t * 8 + i;
    v[i] = (idx < B) ? btot[idx] : 0;
    s += v[i];
  }
  int incl = s;
#pragma unroll
  for (int off = 1; off < 64; off <<= 1) {
    int u = __shfl_up(incl, off);
    if (lane >= off) incl += u;
  }
  if (lane == 63) wsum[w] = incl;
  __syncthreads();
  int run = incl - s;
  for (int w2 = 0; w2 < w; ++w2) run += wsum[w2];
#pragma unroll
  for (int i = 0; i < 8; ++i) {
    int idx = t * 8 + i;
    if (idx <= B) base[idx] = run;
    run += v[i];
  }
}

__global__ __launch_bounds__(256) void
a2_scatter_k(const int* __restrict__ row, const int* __restrict__ col,
             const float* __restrict__ val, const int* __restrict__ base,
             const int* __restrict__ offGB, int2* __restrict__ stage,
             int nnz, int B, int chunk) {
  __shared__ int cur[BMAX];
  int g = blockIdx.x;
  for (int i = threadIdx.x; i < B; i += 256)
    cur[i] = base[i] + offGB[i * G_BLOCKS + g];
  __syncthreads();
  int s = g * chunk, e = min(nnz, s + chunk);
  int j = s + threadIdx.x;
  for (; j + 768 < e; j += 1024) {
    int r0 = row[j], r1 = row[j + 256], r2 = row[j + 512], r3 = row[j + 768];
    int c0 = col[j], c1 = col[j + 256], c2 = col[j + 512], c3 = col[j + 768];
    float v0 = val[j], v1 = val[j + 256], v2 = val[j + 512], v3 = val[j + 768];
    int p0 = atomicAdd(&cur[r0 >> 7], 1);
    int p1 = atomicAdd(&cur[r1 >> 7], 1);
    int p2 = atomicAdd(&cur[r2 >> 7], 1);
    int p3 = atomicAdd(&cur[r3 >> 7], 1);
    int2 q0; q0.x = ((r0 & 127) << 24) | c0; q0.y = __float_as_int(v0);
    int2 q1; q1.x = ((r1 & 127) << 24) | c1; q1.y = __float_as_int(v1);
    int2 q2; q2.x = ((r2 & 127) << 24) | c2; q2.y = __float_as_int(v2);
    int2 q3; q3.x = ((r3 & 127) << 24) | c3; q3.y = __float_as_int(v3);
    stage[p0] = q0;
    stage[p1] = q1;
    stage[p2] = q2;
    stage[p3] = q3;
  }
  for (; j < e; j += 256) {
    int r = row[j];
    int pos = atomicAdd(&cur[r >> 7], 1);
    int2 p;
    p.x = ((r & 127) << 24) | col[j];
    p.y = __float_as_int(val[j]);
    stage[pos] = p;
  }
}

// ---------------- SpMM with in-LDS (col-phase, row)-sorted CSR build ----------------
// One block per 128-row bucket, 512 threads (8 waves x 16 rows).
// Build: LDS hist over key=(col>>14)*128+row -> scan -> LDS edge list sorted by
// (phase,row). Gather: loop phases outer; all co-resident blocks touch the same
// 4.2MB x-slice per phase -> per-XCD L2 resident. acc[16] in registers across
// phases (statically indexed). No LDS atomics in the hot loop.

__global__ __launch_bounds__(512) void
spmm_csr_k(const int* __restrict__ base, const int2* __restrict__ stage,
           const float* __restrict__ x, float* __restrict__ y, int n, int nph) {
  __shared__ int2 ebuf[CAP];
  __shared__ int rowoff[NKEY], cur[NKEY];
  __shared__ int wsum[8];
  int b = blockIdx.x, t = threadIdx.x;
  int lane = t & 63, w = t >> 6;
  cur[t] = 0; cur[t + 512] = 0;
  __syncthreads();
  int s = __builtin_amdgcn_readfirstlane(base[b]);
  int e = __builtin_amdgcn_readfirstlane(base[b + 1]);
  int cnt = e - s;
  if (cnt <= CAP) {
    // hist over 1024 keys
    for (int j = s + t; j < e; j += 512) {
      int2 p = stage[j];
      int key = (((p.x & 0xFFFFFF) >> PH_SHIFT) << 7) | (((unsigned)p.x) >> 24);
      atomicAdd(&cur[key], 1);
    }
    __syncthreads();
    // exclusive scan of 1024 counters; thread t owns entries 2t, 2t+1
    int v0 = cur[2 * t], v1 = cur[2 * t + 1];
    int s2 = v0 + v1;
    int incl = s2;
#pragma unroll
    for (int off = 1; off < 64; off <<= 1) {
      int u = __shfl_up(incl, off);
      if (lane >= off) incl += u;
    }
    if (lane == 63) wsum[w] = incl;
    __syncthreads();
    int run = incl - s2;
    for (int w2 = 0; w2 < w; ++w2) run += wsum[w2];
    rowoff[2 * t] = run;
    rowoff[2 * t + 1] = run + v0;
    cur[2 * t] = run;
    cur[2 * t + 1] = run + v0;
    __syncthreads();
    // scatter into (phase,row)-sorted LDS list
    for (int j = s + t; j < e; j += 512) {
      int2 p = stage[j];
      int key = (((p.x & 0xFFFFFF) >> PH_SHIFT) << 7) | (((unsigned)p.x) >> 24);
      int pos = atomicAdd(&cur[key], 1);
      int2 q; q.x = p.x & 0xFFFFFF; q.y = p.y;
      ebuf[pos] = q;
    }
    __syncthreads();
    // gather: wave w owns rows w*16..w*16+15; phases outer, acc in regs
    float acc[16];
#pragma unroll
    for (int i = 0; i < 16; ++i) acc[i] = 0.f;
    for (int p = 0; p < nph; ++p) {
#pragma unroll
      for (int i = 0; i < 16; ++i) {
        int key = (p << 7) | (w * 16 + i);
        int k   = __builtin_amdgcn_readfirstlane(rowoff[key]);
        int end = __builtin_amdgcn_readfirstlane(cur[key]);
        float a = acc[i];
        for (; k + 4 <= end; k += 4) {
          int2 q0 = ebuf[k], q1 = ebuf[k + 1], q2 = ebuf[k + 2], q3 = ebuf[k + 3];
          float x0 = x[((size_t)q0.x << 6) + lane];
          float x1 = x[((size_t)q1.x << 6) + lane];
          float x2 = x[((size_t)q2.x << 6) + lane];
          float x3 = x[((size_t)q3.x << 6) + lane];
          a += __int_as_float(q0.y) * x0;
          a += __int_as_float(q1.y) * x1;
          a += __int_as_float(q2.y) * x2;
          a += __int_as_float(q3.y) * x3;
        }
        for (; k < end; ++k) {
          int2 q = ebuf[k];
          a += __int_as_float(q.y) * x[((size_t)q.x << 6) + lane];
        }
        acc[i] = a;
      }
    }
#pragma unroll
    for (int i = 0; i < 16; ++i) {
      int R = (b << 7) + w * 16 + i;
      if (R < n) y[((size_t)R << 6) + lane] = acc[i];
    }
  } else {
    // degenerate guard (cnt > CAP): never taken for this input
    for (int rr = w * 16; rr < w * 16 + 16; ++rr) {
      int R = (b << 7) + rr;
      if (R >= n) continue;
      float acc = 0.f;
      for (int j = s; j < e; ++j) {
        int2 p = stage[j];
        if ((int)(((unsigned)p.x) >> 24) == rr)
          acc += __int_as_float(p.y) * x[((size_t)(p.x & 0xFFFFFF) << 6) + lane];
      }
      y[((size_t)R << 6) + lane] = acc;
    }
  }
}

__global__ __launch_bounds__(512) void
spmm_csr_fused_k(const int* __restrict__ base, const int2* __restrict__ stage,
                 const float* __restrict__ e0g, const float* __restrict__ e1g,
                 float* __restrict__ e2g, float* __restrict__ summed,
                 float* __restrict__ e0out, int n, int nph) {
  __shared__ int2 ebuf[CAP];
  __shared__ int rowoff[NKEY], cur[NKEY];
  __shared__ int wsum[8];
  int b = blockIdx.x, t = threadIdx.x;
  int lane = t & 63, w = t >> 6;
  cur[t] = 0; cur[t + 512] = 0;
  __syncthreads();
  int s = __builtin_amdgcn_readfirstlane(base[b]);
  int e = __builtin_amdgcn_readfirstlane(base[b + 1]);
  int cnt = e - s;
  if (cnt <= CAP) {
    for (int j = s + t; j < e; j += 512) {
      int2 p = stage[j];
      int key = (((p.x & 0xFFFFFF) >> PH_SHIFT) << 7) | (((unsigned)p.x) >> 24);
      atomicAdd(&cur[key], 1);
    }
    __syncthreads();
    int v0 = cur[2 * t], v1 = cur[2 * t + 1];
    int s2 = v0 + v1;
    int incl = s2;
#pragma unroll
    for (int off = 1; off < 64; off <<= 1) {
      int u = __shfl_up(incl, off);
      if (lane >= off) incl += u;
    }
    if (lane == 63) wsum[w] = incl;
    __syncthreads();
    int run = incl - s2;
    for (int w2 = 0; w2 < w; ++w2) run += wsum[w2];
    rowoff[2 * t] = run;
    rowoff[2 * t + 1] = run + v0;
    cur[2 * t] = run;
    cur[2 * t + 1] = run + v0;
    __syncthreads();
    for (int j = s + t; j < e; j += 512) {
      int2 p = stage[j];
      int key = (((p.x & 0xFFFFFF) >> PH_SHIFT) << 7) | (((unsigned)p.x) >> 24);
      int pos = atomicAdd(&cur[key], 1);
      int2 q; q.x = p.x & 0xFFFFFF; q.y = p.y;
      ebuf[pos] = q;
    }
    __syncthreads();
    float acc[16];
#pragma unroll
    for (int i = 0; i < 16; ++i) acc[i] = 0.f;
    for (int p = 0; p < nph; ++p) {
#pragma unroll
      for (int i = 0; i < 16; ++i) {
        int key = (p << 7) | (w * 16 + i);
        int k   = __builtin_amdgcn_readfirstlane(rowoff[key]);
        int end = __builtin_amdgcn_readfirstlane(cur[key]);
        float a = acc[i];
        for (; k + 4 <= end; k += 4) {
          int2 q0 = ebuf[k], q1 = ebuf[k + 1], q2 = ebuf[k + 2], q3 = ebuf[k + 3];
          float x0 = e1g[((size_t)q0.x << 6) + lane];
          float x1 = e1g[((size_t)q1.x << 6) + lane];
          float x2 = e1g[((size_t)q2.x << 6) + lane];
          float x3 = e1g[((size_t)q3.x << 6) + lane];
          a += __int_as_float(q0.y) * x0;
          a += __int_as_float(q1.y) * x1;
          a += __int_as_float(q2.y) * x2;
          a += __int_as_float(q3.y) * x3;
        }
        for (; k < end; ++k) {
          int2 q = ebuf[k];
          a += __int_as_float(q.y) * e1g[((size_t)q.x << 6) + lane];
        }
        acc[i] = a;
      }
    }
#pragma unroll
    for (int i = 0; i < 16; ++i) {
      int R = (b << 7) + w * 16 + i;
      if (R < n) {
        size_t o = ((size_t)R << 6) + lane;
        float v0f = e0g[o];
        float v1f = e1g[o];
        e2g[o] = acc[i];
        summed[o] = v0f + v1f + acc[i];
        e0out[o] = v0f;
      }
    }
  } else {
    for (int rr = w * 16; rr < w * 16 + 16; ++rr) {
      int R = (b << 7) + rr;
      if (R >= n) continue;
      float acc = 0.f;
      for (int j = s; j < e; ++j) {
        int2 p = stage[j];
        if ((int)(((unsigned)p.x) >> 24) == rr)
          acc += __int_as_float(p.y) * e1g[((size_t)(p.x & 0xFFFFFF) << 6) + lane];
      }
      size_t o = ((size_t)R << 6) + lane;
      float v0 = e0g[o];
      float v1 = e1g[o];
      e2g[o] = acc;
      summed[o] = v0 + v1 + acc;
      e0out[o] = v0;
    }
  }
}

// ---------------- fallback: atomic path ----------------

__global__ void spmm_atomic_k(const int* __restrict__ row, const int* __restrict__ col,
                              const float* __restrict__ val, const float* __restrict__ x,
                              float* __restrict__ y, int nnz) {
  int wave = (blockIdx.x * blockDim.x + threadIdx.x) >> 6;
  int lane = threadIdx.x & 63;
  if (wave >= nnz) return;
  int r = row[wave]; int c = col[wave]; float v = val[wave];
  atomicAdd(&y[(size_t)r * DHID + lane], v * x[(size_t)c * DHID + lane]);
}

__global__ void sum_k(const float4* __restrict__ e0, const float4* __restrict__ e1,
                      const float4* __restrict__ e2, float4* __restrict__ summed,
                      float4* __restrict__ e0out, int n4) {
  int i = blockIdx.x * blockDim.x + threadIdx.x;
  if (i < n4) {
    float4 a = e0[i], b = e1[i], c = e2[i];
    float4 s;
    s.x = a.x + b.x + c.x;
    s.y = a.y + b.y + c.y;
    s.z = a.z + b.z + c.z;
    s.w = a.w + b.w + c.w;
    summed[i] = s;
    e0out[i] = a;
  }
}

extern "C" void kernel_launch(void* const* d_in, const int* in_sizes, int n_in,
                              void* d_out, int out_size, void* d_ws, size_t ws_size,
                              hipStream_t stream) {
  const int*   row = (const int*)d_in[0];
  const int*   col = (const int*)d_in[1];
  const float* val = (const float*)d_in[2];
  const float* emb = (const float*)d_in[3];
  int nnz = in_sizes[0];
  int n   = in_sizes[3] / DHID;
  size_t ND = (size_t)n * DHID;

  float* out    = (float*)d_out;
  float* summed = out;
  float* e0o    = out + ND;
  float* e1     = out + 2 * ND;
  float* e2     = out + 3 * ND;

  int B  = (n + RPB - 1) / RPB;          // buckets of 128 rows
  int nph = (n + (1 << PH_SHIFT) - 1) >> PH_SHIFT;  // column phases
  int chunk = (nnz + G_BLOCKS - 1) / G_BLOCKS;

  // carve workspace
  size_t o0 = 0;
  size_t histGB_off = o0; o0 += align256((size_t)B * G_BLOCKS * 4);
  size_t offGB_off  = o0; o0 += align256((size_t)B * G_BLOCKS * 4);
  size_t btot_off   = o0; o0 += align256((size_t)B * 4);
  size_t base_off   = o0; o0 += align256((size_t)(B + 1) * 4);
  size_t stage_off  = o0; o0 += align256((size_t)nnz * 8);
  size_t need_sorted = o0;

  bool use_sorted = (ws_size >= need_sorted) && (B <= BMAX) && (n < (1 << 24)) &&
                    (nph <= NPHMAX);

  int n4 = (int)(ND / 4);
  int sb = (n4 + 255) / 256;
  int wb = (int)(((size_t)nnz * 64 + 255) / 256);

  if (use_sorted) {
    uint8_t* w = (uint8_t*)d_ws;
    int*  histGB = (int*)(w + histGB_off);
    int*  offGB  = (int*)(w + offGB_off);
    int*  btot   = (int*)(w + btot_off);
    int*  base   = (int*)(w + base_off);
    int2* stage  = (int2*)(w + stage_off);

    // phase A: partition into 128-row buckets, zero global atomics
    a1_hist_k<<<G_BLOCKS, 256, 0, stream>>>(row, histGB, nnz, B, chunk);
    scan_gb_k<<<B, 256, 0, stream>>>(histGB, offGB, btot, B);
    scan_b_k<<<1, 256, 0, stream>>>(btot, base, B);
    a2_scatter_k<<<G_BLOCKS, 256, 0, stream>>>(row, col, val, base, offGB, stage,
                                               nnz, B, chunk);

    // SpMM x2 with in-LDS phase-sorted CSR build (layer 2 fuses the epilogue)
    spmm_csr_k<<<B, 512, 0, stream>>>(base, stage, emb, e1, n, nph);
    spmm_csr_fused_k<<<B, 512, 0, stream>>>(base, stage, emb, e1, e2, summed, e0o,
                                            n, nph);
  } else {
    zero_f32<<<(int)((ND + 255) / 256), 256, 0, stream>>>(e1, ND);
    spmm_atomic_k<<<wb, 256, 0, stream>>>(row, col, val, emb, e1, nnz);
    zero_f32<<<(int)((ND + 255) / 256), 256, 0, stream>>>(e2, ND);
    spmm_atomic_k<<<wb, 256, 0, stream>>>(row, col, val, e1, e2, nnz);
    sum_k<<<sb, 256, 0, stream>>>((const float4*)emb, (const float4*)e1,
                                  (const float4*)e2, (float4*)summed,
                                  (float4*)e0o, n4);
  }
}